// Round 11
// baseline (664.594 us; speedup 1.0000x reference)
//
#include <hip/hip_runtime.h>
#include <hip/hip_bf16.h>

// Problem constants (B=2, S=1024, E=1024, H=16, D=64)
#define S_LEN 1024
#define E_DIM 1024
#define NH 16
#define HD 64
#define M_ROWS 2048   // B*S
#define BH_CNT 32     // B*NH

static constexpr float LR_C = 0.01f;
static constexpr float SC_C = 0.125f;            // 1/sqrt(64)
static constexpr float C2_C = 0.125f * 1.44269504f;  // SC * log2(e): scores -> log2 domain

typedef unsigned short ushort_t;
typedef __attribute__((ext_vector_type(8))) __bf16 bf16x8;
typedef __attribute__((ext_vector_type(4))) float f32x4;

static __device__ inline ushort_t f2bu(float f) {
  __hip_bfloat16 h = __float2bfloat16(f);
  return *(ushort_t*)&h;
}
static __device__ inline bf16x8 ldg8(const ushort_t* p) { return *(const bf16x8*)p; }

// ---------------- weight prep: bf16 cast + bf16 transpose, 64x64 tiles ----------------
__global__ __launch_bounds__(256) void prep_w(const float* __restrict__ W,
                                              ushort_t* __restrict__ Wb,
                                              ushort_t* __restrict__ WTb) {
  __shared__ float ts[64][65];
  int bx = blockIdx.x * 64, by = blockIdx.y * 64;
  int t = threadIdx.x;
  int rr = t >> 6, cc = t & 63;
  #pragma unroll
  for (int p = 0; p < 16; p++) {
    int r = p * 4 + rr;
    float v = W[(size_t)(by + r) * E_DIM + bx + cc];
    ts[r][cc] = v;
    Wb[(size_t)(by + r) * E_DIM + bx + cc] = f2bu(v);
  }
  __syncthreads();
  #pragma unroll
  for (int p = 0; p < 16; p++) {
    int r = p * 4 + rr;
    WTb[(size_t)(bx + r) * E_DIM + by + cc] = f2bu(ts[cc][r]);
  }
}

// ---------------- bf16 MFMA GEMM, 64x64 tile: C[2048,1024] = A*B^T ----------------
// MODE 0: Cb_z = bf16(acc) + Ct_z transposed [bh][d][token]   [QKV proj]
// MODE 1: Cb0 = bf16(T - acc)                                 [stage-1 residual]
// MODE 2: Cf += alpha*acc (fp32) and Cb0 = bf16(Cf), NSEG K-segments [PC update]
template <int MODE, int NSEG>
__global__ __launch_bounds__(256) void gemm_mf(
    const ushort_t* __restrict__ A0, const ushort_t* __restrict__ A1, const ushort_t* __restrict__ A2,
    const ushort_t* __restrict__ B0, const ushort_t* __restrict__ B1, const ushort_t* __restrict__ B2,
    float* __restrict__ Cf, const float* __restrict__ T,
    ushort_t* __restrict__ Cb0, ushort_t* __restrict__ Cb1, ushort_t* __restrict__ Cb2,
    ushort_t* __restrict__ Ct0, ushort_t* __restrict__ Ct1, ushort_t* __restrict__ Ct2,
    float alpha) {
  const int K = 1024;
  __shared__ __bf16 As[64][40];
  __shared__ __bf16 Bs[64][40];
  int tid = threadIdx.x;
  int m0 = blockIdx.y * 64, n0 = blockIdx.x * 64;

  const ushort_t* Bsel = B0;
  ushort_t* Cbz = Cb0;
  ushort_t* Ctz = Ct0;
  if (MODE == 0) {
    int z = blockIdx.z;
    Bsel = (z == 0) ? B0 : (z == 1) ? B1 : B2;
    Cbz = (z == 0) ? Cb0 : (z == 1) ? Cb1 : Cb2;
    Ctz = (z == 0) ? Ct0 : (z == 1) ? Ct1 : Ct2;
  }

  int lane = tid & 63, wave = tid >> 6;
  int wrow = wave >> 1, wcol = wave & 1;
  int fr = lane & 15, q = lane >> 4;

  f32x4 acc[2][2] = {};

  int ar = tid >> 2, ac = (tid & 3) * 8;
  #pragma unroll 1
  for (int seg = 0; seg < NSEG; seg++) {
    const ushort_t* Aseg = (seg == 0) ? A0 : (seg == 1) ? A1 : A2;
    const ushort_t* Bseg = (MODE == 0) ? Bsel : ((seg == 0) ? B0 : (seg == 1) ? B1 : B2);
    const ushort_t* Ag = Aseg + (size_t)(m0 + ar) * K + ac;
    const ushort_t* Bg = Bseg + (size_t)(n0 + ar) * K + ac;
    for (int k0 = 0; k0 < K; k0 += 32) {
      uint4 av = *(const uint4*)(Ag + k0);
      uint4 bv = *(const uint4*)(Bg + k0);
      __syncthreads();
      *(uint4*)&As[ar][ac] = av;
      *(uint4*)&Bs[ar][ac] = bv;
      __syncthreads();
      bf16x8 a0 = *(const bf16x8*)&As[wrow * 32 + fr][q * 8];
      bf16x8 a1 = *(const bf16x8*)&As[wrow * 32 + 16 + fr][q * 8];
      bf16x8 b0 = *(const bf16x8*)&Bs[wcol * 32 + fr][q * 8];
      bf16x8 b1 = *(const bf16x8*)&Bs[wcol * 32 + 16 + fr][q * 8];
      acc[0][0] = __builtin_amdgcn_mfma_f32_16x16x32_bf16(a0, b0, acc[0][0], 0, 0, 0);
      acc[0][1] = __builtin_amdgcn_mfma_f32_16x16x32_bf16(a0, b1, acc[0][1], 0, 0, 0);
      acc[1][0] = __builtin_amdgcn_mfma_f32_16x16x32_bf16(a1, b0, acc[1][0], 0, 0, 0);
      acc[1][1] = __builtin_amdgcn_mfma_f32_16x16x32_bf16(a1, b1, acc[1][1], 0, 0, 0);
    }
  }

  // C/D layout: col = lane&15, row = (lane>>4)*4 + reg
  #pragma unroll
  for (int mi = 0; mi < 2; mi++)
    #pragma unroll
    for (int ni = 0; ni < 2; ni++) {
      int col = n0 + wcol * 32 + ni * 16 + fr;
      int row0 = m0 + wrow * 32 + mi * 16 + q * 4;
      ushort_t pk[4];
      #pragma unroll
      for (int r = 0; r < 4; r++) {
        size_t idx = (size_t)(row0 + r) * E_DIM + col;
        float v = acc[mi][ni][r];
        if (MODE == 0) {
          ushort_t bu = f2bu(v);
          pk[r] = bu;
          Cbz[idx] = bu;
        } else if (MODE == 1) {
          Cb0[idx] = f2bu(T[idx] - v);
        } else {
          float nv = Cf[idx] + alpha * v;
          Cf[idx] = nv;
          Cb0[idx] = f2bu(nv);
        }
      }
      if (MODE == 0) {
        int hh = col >> 6, dd = col & 63;
        int bb = row0 >> 10, ss = row0 & 1023;
        *(uint2*)(Ctz + ((size_t)((bb * NH + hh) * HD + dd)) * S_LEN + ss) = *(uint2*)pk;
      }
    }
}

// ====================== MFMA attention, LDS-staged ======================

// ---- fused fwd: single-pass flash, log2-domain online softmax; emits m(log2-scaled),
//      1/l, g=O-Xs (bf16 + transposed), Dv. grid (bh=32, y=16), balanced pairing. ----
__global__ __launch_bounds__(256) void fwd_fused(const ushort_t* __restrict__ Qg,
                                                 const ushort_t* __restrict__ Kg,
                                                 const ushort_t* __restrict__ Vt,
                                                 const float* __restrict__ Xs,
                                                 float* __restrict__ mbuf,
                                                 float* __restrict__ lbuf,
                                                 ushort_t* __restrict__ Gb,
                                                 ushort_t* __restrict__ Gt,
                                                 float* __restrict__ Dv) {
  int bh = blockIdx.x, y = blockIdx.y;
  int it = (y < 8) ? (15 - y) : (y - 8);
  int b = bh >> 4, h = bh & 15;
  int tid = threadIdx.x, lane = tid & 63, wv = tid >> 6;
  int fr = lane & 15, q = lane >> 4;
  int i0 = it * 64, band = wv * 16;
  __shared__ ushort_t Kts[64][72];  // [j][d]
  __shared__ ushort_t Vts[64][72];  // [d][j]
  __shared__ ushort_t Ps[64][72];   // [i][j] wave-private bands

  const ushort_t* Qrow = Qg + (size_t)(b * S_LEN + i0 + band + fr) * E_DIM + h * HD;
  bf16x8 aq0 = ldg8(Qrow + q * 8);
  bf16x8 aq1 = ldg8(Qrow + 32 + q * 8);

  float m[4], l[4];
  #pragma unroll
  for (int r = 0; r < 4; r++) { m[r] = -1e30f; l[r] = 0.f; }
  f32x4 oacc[4] = {};

  #pragma unroll 1
  for (int jt = 0; jt <= it; jt++) {
    int j0 = jt * 64;
    __syncthreads();
    #pragma unroll
    for (int t = 0; t < 2; t++) {
      int u = tid + 256 * t;
      int r = u >> 3, c8 = (u & 7) * 8;
      *(uint4*)&Kts[r][c8] = *(const uint4*)(Kg + (size_t)(b * S_LEN + j0 + r) * E_DIM + h * HD + c8);
      *(uint4*)&Vts[r][c8] = *(const uint4*)(Vt + (size_t)(bh * HD + r) * S_LEN + j0 + c8);
    }
    __syncthreads();
    f32x4 sA[4];
    #pragma unroll
    for (int nc = 0; nc < 4; nc++) {
      bf16x8 bk0 = *(const bf16x8*)&Kts[nc * 16 + fr][q * 8];
      bf16x8 bk1 = *(const bf16x8*)&Kts[nc * 16 + fr][32 + q * 8];
      f32x4 z = {};
      z = __builtin_amdgcn_mfma_f32_16x16x32_bf16(aq0, bk0, z, 0, 0, 0);
      sA[nc] = __builtin_amdgcn_mfma_f32_16x16x32_bf16(aq1, bk1, z, 0, 0, 0);
    }
    float sv[4][4];
    #pragma unroll
    for (int nc = 0; nc < 4; nc++)
      #pragma unroll
      for (int r = 0; r < 4; r++) {
        int row = i0 + band + q * 4 + r;
        int col = j0 + nc * 16 + fr;
        sv[nc][r] = (col <= row) ? sA[nc][r] * C2_C : -1e30f;  // log2 domain
      }
    #pragma unroll
    for (int r = 0; r < 4; r++) {
      float mx = fmaxf(fmaxf(sv[0][r], sv[1][r]), fmaxf(sv[2][r], sv[3][r]));
      #pragma unroll
      for (int off = 1; off < 16; off <<= 1) mx = fmaxf(mx, __shfl_xor(mx, off, 64));
      float mn = fmaxf(m[r], mx);
      float alpha = exp2f(m[r] - mn);
      float ps = 0.f;
      #pragma unroll
      for (int nc = 0; nc < 4; nc++) {
        float p = exp2f(sv[nc][r] - mn);
        Ps[band + q * 4 + r][nc * 16 + fr] = f2bu(p);
        ps += p;
      }
      #pragma unroll
      for (int off = 1; off < 16; off <<= 1) ps += __shfl_xor(ps, off, 64);
      l[r] = l[r] * alpha + ps;
      m[r] = mn;
      #pragma unroll
      for (int nc = 0; nc < 4; nc++) oacc[nc][r] *= alpha;
    }
    bf16x8 ap0 = *(const bf16x8*)&Ps[band + fr][q * 8];
    bf16x8 ap1 = *(const bf16x8*)&Ps[band + fr][32 + q * 8];
    #pragma unroll
    for (int nc = 0; nc < 4; nc++) {
      bf16x8 bv0 = *(const bf16x8*)&Vts[nc * 16 + fr][q * 8];
      bf16x8 bv1 = *(const bf16x8*)&Vts[nc * 16 + fr][32 + q * 8];
      oacc[nc] = __builtin_amdgcn_mfma_f32_16x16x32_bf16(ap0, bv0, oacc[nc], 0, 0, 0);
      oacc[nc] = __builtin_amdgcn_mfma_f32_16x16x32_bf16(ap1, bv1, oacc[nc], 0, 0, 0);
    }
  }
  // epilogue: g = O - Xs (bf16 normal + transposed), Dv partials
  float linv[4];
  #pragma unroll
  for (int r = 0; r < 4; r++) linv[r] = 1.0f / l[r];
  float dpart[4] = {};
  #pragma unroll
  for (int nc = 0; nc < 4; nc++) {
    ushort_t pg[4];
    #pragma unroll
    for (int r = 0; r < 4; r++) {
      int row = i0 + band + q * 4 + r;
      size_t gi = (size_t)(b * S_LEN + row) * E_DIM + h * HD + nc * 16 + fr;
      float o = oacc[nc][r] * linv[r];
      float g = o - Xs[gi];
      ushort_t bu = f2bu(g);
      Gb[gi] = bu;
      pg[r] = bu;
      dpart[r] += g * o;
    }
    int d = nc * 16 + fr;
    int s0 = i0 + band + q * 4;
    *(uint2*)(Gt + ((size_t)bh * HD + d) * S_LEN + s0) = *(uint2*)pg;
  }
  #pragma unroll
  for (int r = 0; r < 4; r++) {
    #pragma unroll
    for (int off = 1; off < 16; off <<= 1) dpart[r] += __shfl_xor(dpart[r], off, 64);
  }
  if (fr == 0) {
    #pragma unroll
    for (int r = 0; r < 4; r++) {
      size_t sid = (size_t)bh * S_LEN + i0 + band + q * 4 + r;
      mbuf[sid] = m[r];      // already log2-scaled
      lbuf[sid] = linv[r];
      Dv[sid] = dpart[r];
    }
  }
}

// ---- split backward: grid (bh=32, y=32), 1024 blocks = 4/CU, 36.9 KB LDS.
//      y<16: dq for i-tile y (y+1 units).  y>=16: dk/dv for j-tile y-16 (32-y units).
//      Per-CU sum under mod-256 round-robin = 34 units, constant. ----
__global__ __launch_bounds__(256) void bwd_split(const ushort_t* __restrict__ Qg,
                                                 const ushort_t* __restrict__ Kg,
                                                 const ushort_t* __restrict__ Vg,
                                                 const ushort_t* __restrict__ Gg,
                                                 const ushort_t* __restrict__ Qt,
                                                 const ushort_t* __restrict__ Kt,
                                                 const ushort_t* __restrict__ Gt,
                                                 const float* __restrict__ mbuf,
                                                 const float* __restrict__ lbuf,
                                                 const float* __restrict__ Dv,
                                                 ushort_t* __restrict__ GQ,
                                                 ushort_t* __restrict__ GK,
                                                 ushort_t* __restrict__ GV) {
  int bh = blockIdx.x, y = blockIdx.y;
  int b = bh >> 4, h = bh & 15;
  int tid = threadIdx.x, lane = tid & 63, wv = tid >> 6;
  int fr = lane & 15, q = lane >> 4;
  int band = wv * 16;
  __shared__ ushort_t smem[4][64][72];  // 36.9 KB -> 4 blocks/CU

  if (y < 16) {
    // ============ dq for i-tile y ============
    ushort_t (*Kts)[72] = smem[0];  // [j][d]
    ushort_t (*Vts)[72] = smem[1];  // [j][d]
    ushort_t (*Ktt)[72] = smem[2];  // [d][j]
    ushort_t (*dSs)[72] = smem[3];
    int it = y, i0 = it * 64;

    const ushort_t* Qrow = Qg + (size_t)(b * S_LEN + i0 + band + fr) * E_DIM + h * HD;
    const ushort_t* Grow = Gg + (size_t)(b * S_LEN + i0 + band + fr) * E_DIM + h * HD;
    bf16x8 aq0 = ldg8(Qrow + q * 8), aq1 = ldg8(Qrow + 32 + q * 8);
    bf16x8 ag0 = ldg8(Grow + q * 8), ag1 = ldg8(Grow + 32 + q * 8);

    float mrow[4], linv[4], Dr[4];
    #pragma unroll
    for (int r = 0; r < 4; r++) {
      size_t sid = (size_t)bh * S_LEN + i0 + band + q * 4 + r;
      mrow[r] = mbuf[sid]; linv[r] = lbuf[sid]; Dr[r] = Dv[sid];
    }
    f32x4 dqacc[4] = {};

    #pragma unroll 1
    for (int jt = 0; jt <= it; jt++) {
      int j0 = jt * 64;
      __syncthreads();
      #pragma unroll
      for (int t = 0; t < 2; t++) {
        int u = tid + 256 * t;
        int r = u >> 3, c8 = (u & 7) * 8;
        *(uint4*)&Kts[r][c8] = *(const uint4*)(Kg + (size_t)(b * S_LEN + j0 + r) * E_DIM + h * HD + c8);
        *(uint4*)&Vts[r][c8] = *(const uint4*)(Vg + (size_t)(b * S_LEN + j0 + r) * E_DIM + h * HD + c8);
        *(uint4*)&Ktt[r][c8] = *(const uint4*)(Kt + (size_t)(bh * HD + r) * S_LEN + j0 + c8);
      }
      __syncthreads();
      f32x4 sA[4], dpA[4];
      #pragma unroll
      for (int nc = 0; nc < 4; nc++) {
        bf16x8 bk0 = *(const bf16x8*)&Kts[nc * 16 + fr][q * 8];
        bf16x8 bk1 = *(const bf16x8*)&Kts[nc * 16 + fr][32 + q * 8];
        bf16x8 bv0 = *(const bf16x8*)&Vts[nc * 16 + fr][q * 8];
        bf16x8 bv1 = *(const bf16x8*)&Vts[nc * 16 + fr][32 + q * 8];
        f32x4 z = {};
        z = __builtin_amdgcn_mfma_f32_16x16x32_bf16(aq0, bk0, z, 0, 0, 0);
        sA[nc] = __builtin_amdgcn_mfma_f32_16x16x32_bf16(aq1, bk1, z, 0, 0, 0);
        f32x4 z2 = {};
        z2 = __builtin_amdgcn_mfma_f32_16x16x32_bf16(ag0, bv0, z2, 0, 0, 0);
        dpA[nc] = __builtin_amdgcn_mfma_f32_16x16x32_bf16(ag1, bv1, z2, 0, 0, 0);
      }
      #pragma unroll
      for (int nc = 0; nc < 4; nc++)
        #pragma unroll
        for (int r = 0; r < 4; r++) {
          int row = i0 + band + q * 4 + r;
          int col = j0 + nc * 16 + fr;
          float ds = 0.f;
          if (col <= row) {
            float P = exp2f(fmaf(sA[nc][r], C2_C, -mrow[r])) * linv[r];
            ds = P * (dpA[nc][r] - Dr[r]) * SC_C;
          }
          dSs[band + q * 4 + r][nc * 16 + fr] = f2bu(ds);  // wave-private
        }
      bf16x8 ad0 = *(const bf16x8*)&dSs[band + fr][q * 8];
      bf16x8 ad1 = *(const bf16x8*)&dSs[band + fr][32 + q * 8];
      #pragma unroll
      for (int nc = 0; nc < 4; nc++) {
        bf16x8 bt0 = *(const bf16x8*)&Ktt[nc * 16 + fr][q * 8];
        bf16x8 bt1 = *(const bf16x8*)&Ktt[nc * 16 + fr][32 + q * 8];
        dqacc[nc] = __builtin_amdgcn_mfma_f32_16x16x32_bf16(ad0, bt0, dqacc[nc], 0, 0, 0);
        dqacc[nc] = __builtin_amdgcn_mfma_f32_16x16x32_bf16(ad1, bt1, dqacc[nc], 0, 0, 0);
      }
    }
    #pragma unroll
    for (int nc = 0; nc < 4; nc++)
      #pragma unroll
      for (int r = 0; r < 4; r++) {
        int row = i0 + band + q * 4 + r;
        size_t gi = (size_t)(b * S_LEN + row) * E_DIM + h * HD + nc * 16 + fr;
        GQ[gi] = f2bu(dqacc[nc][r]);
      }
  } else {
    // ============ dk/dv for j-tile y-16 ============
    // smem[0]=Qs_ [i][d] (later PT [j][i]); smem[1]=Gs_ [i][d] (later dST);
    // smem[2]=Qtt [d][i]; smem[3]=Gtt [d][i]
    ushort_t (*Qs_)[72] = smem[0];
    ushort_t (*Gs_)[72] = smem[1];
    ushort_t (*Qtt)[72] = smem[2];
    ushort_t (*Gtt)[72] = smem[3];
    int jt = y - 16, j0 = jt * 64;

    const ushort_t* Krow = Kg + (size_t)(b * S_LEN + j0 + band + fr) * E_DIM + h * HD;
    const ushort_t* Vrow = Vg + (size_t)(b * S_LEN + j0 + band + fr) * E_DIM + h * HD;
    bf16x8 ak0 = ldg8(Krow + q * 8), ak1 = ldg8(Krow + 32 + q * 8);
    bf16x8 av0 = ldg8(Vrow + q * 8), av1 = ldg8(Vrow + 32 + q * 8);

    f32x4 dkacc[4] = {}, dvacc[4] = {};

    #pragma unroll 1
    for (int i_t = jt; i_t < 16; i_t++) {
      int i0 = i_t * 64;
      __syncthreads();
      #pragma unroll
      for (int t = 0; t < 2; t++) {
        int u = tid + 256 * t;
        int r = u >> 3, c8 = (u & 7) * 8;
        *(uint4*)&Qs_[r][c8] = *(const uint4*)(Qg + (size_t)(b * S_LEN + i0 + r) * E_DIM + h * HD + c8);
        *(uint4*)&Gs_[r][c8] = *(const uint4*)(Gg + (size_t)(b * S_LEN + i0 + r) * E_DIM + h * HD + c8);
        *(uint4*)&Qtt[r][c8] = *(const uint4*)(Qt + (size_t)(bh * HD + r) * S_LEN + i0 + c8);
        *(uint4*)&Gtt[r][c8] = *(const uint4*)(Gt + (size_t)(bh * HD + r) * S_LEN + i0 + c8);
      }
      __syncthreads();
      float mc[4], lc[4], Dc[4];
      #pragma unroll
      for (int nc = 0; nc < 4; nc++) {
        size_t sid = (size_t)bh * S_LEN + i0 + nc * 16 + fr;
        mc[nc] = mbuf[sid]; lc[nc] = lbuf[sid]; Dc[nc] = Dv[sid];
      }
      f32x4 stA[4], dptA[4];
      #pragma unroll
      for (int nc = 0; nc < 4; nc++) {
        bf16x8 bq0 = *(const bf16x8*)&Qs_[nc * 16 + fr][q * 8];
        bf16x8 bq1 = *(const bf16x8*)&Qs_[nc * 16 + fr][32 + q * 8];
        bf16x8 bg0 = *(const bf16x8*)&Gs_[nc * 16 + fr][q * 8];
        bf16x8 bg1 = *(const bf16x8*)&Gs_[nc * 16 + fr][32 + q * 8];
        f32x4 z = {};
        z = __builtin_amdgcn_mfma_f32_16x16x32_bf16(ak0, bq0, z, 0, 0, 0);
        stA[nc] = __builtin_amdgcn_mfma_f32_16x16x32_bf16(ak1, bq1, z, 0, 0, 0);
        f32x4 z2 = {};
        z2 = __builtin_amdgcn_mfma_f32_16x16x32_bf16(av0, bg0, z2, 0, 0, 0);
        dptA[nc] = __builtin_amdgcn_mfma_f32_16x16x32_bf16(av1, bg1, z2, 0, 0, 0);
      }
      __syncthreads();  // all reads of Qs_/Gs_ complete before aliasing as PT/dST
      #pragma unroll
      for (int nc = 0; nc < 4; nc++)
        #pragma unroll
        for (int r = 0; r < 4; r++) {
          int jrow = j0 + band + q * 4 + r;
          int icol = i0 + nc * 16 + fr;
          float P = 0.f, ds = 0.f;
          if (icol >= jrow) {
            P = exp2f(fmaf(stA[nc][r], C2_C, -mc[nc])) * lc[nc];
            ds = P * (dptA[nc][r] - Dc[nc]) * SC_C;
          }
          Qs_[band + q * 4 + r][nc * 16 + fr] = f2bu(P);   // PT, wave-private
          Gs_[band + q * 4 + r][nc * 16 + fr] = f2bu(ds);  // dST, wave-private
        }
      bf16x8 ap0 = *(const bf16x8*)&Qs_[band + fr][q * 8];
      bf16x8 ap1 = *(const bf16x8*)&Qs_[band + fr][32 + q * 8];
      bf16x8 ad0 = *(const bf16x8*)&Gs_[band + fr][q * 8];
      bf16x8 ad1 = *(const bf16x8*)&Gs_[band + fr][32 + q * 8];
      #pragma unroll
      for (int nc = 0; nc < 4; nc++) {
        bf16x8 bg0 = *(const bf16x8*)&Gtt[nc * 16 + fr][q * 8];
        bf16x8 bg1 = *(const bf16x8*)&Gtt[nc * 16 + fr][32 + q * 8];
        bf16x8 bq0 = *(const bf16x8*)&Qtt[nc * 16 + fr][q * 8];
        bf16x8 bq1 = *(const bf16x8*)&Qtt[nc * 16 + fr][32 + q * 8];
        dvacc[nc] = __builtin_amdgcn_mfma_f32_16x16x32_bf16(ap0, bg0, dvacc[nc], 0, 0, 0);
        dvacc[nc] = __builtin_amdgcn_mfma_f32_16x16x32_bf16(ap1, bg1, dvacc[nc], 0, 0, 0);
        dkacc[nc] = __builtin_amdgcn_mfma_f32_16x16x32_bf16(ad0, bq0, dkacc[nc], 0, 0, 0);
        dkacc[nc] = __builtin_amdgcn_mfma_f32_16x16x32_bf16(ad1, bq1, dkacc[nc], 0, 0, 0);
      }
    }
    #pragma unroll
    for (int nc = 0; nc < 4; nc++)
      #pragma unroll
      for (int r = 0; r < 4; r++) {
        int jrow = j0 + band + q * 4 + r;
        size_t gi = (size_t)(b * S_LEN + jrow) * E_DIM + h * HD + nc * 16 + fr;
        GK[gi] = f2bu(dkacc[nc][r]);
        GV[gi] = f2bu(dvacc[nc][r]);
      }
  }
}

// ---------------- launch ----------------
extern "C" void kernel_launch(void* const* d_in, const int* in_sizes, int n_in,
                              void* d_out, int out_size, void* d_ws, size_t ws_size,
                              hipStream_t stream) {
  const float* T1 = (const float*)d_in[0];
  const float* Wq = (const float*)d_in[1];
  const float* Wk = (const float*)d_in[2];
  const float* Wv = (const float*)d_in[3];
  const float* Wo = (const float*)d_in[4];

  const size_t M2 = 2097152;   // 2048*1024
  const size_t M1 = 1048576;
  float* w = (float*)d_ws;
  float* Xs = w;                       // 8 MB fp32 target
  float* mS = Xs + M2;                 // 64K f32
  float* lS = mS + 65536;
  float* DvS = lS + 65536;
  ushort_t* u = (ushort_t*)(DvS + 65536);
  ushort_t* W0 = u;          ushort_t* W1 = W0 + M1;  ushort_t* W2 = W1 + M1;
  ushort_t* W3 = W2 + M1;    ushort_t* W4 = W3 + M1;  ushort_t* W5 = W4 + M1;
  ushort_t* Qb = W5 + M1;    ushort_t* Kb = Qb + M2;  ushort_t* Vb = Kb + M2;
  ushort_t* Qt = Vb + M2;    ushort_t* Kt = Qt + M2;  ushort_t* Vt = Kt + M2;
  ushort_t* Gt = Vt + M2;
  ushort_t* Gb = Gt + M2;
  ushort_t* GQb = Gb + M2;   ushort_t* GKb = GQb + M2; ushort_t* GVb = GKb + M2;
  ushort_t* X2b = GVb + M2;
  ushort_t* Rb = GQb;        // stage-1 aliases
  ushort_t* Xsb = GKb;
  float* X2 = (float*)d_out;

  hipMemsetAsync(Xs, 0, M2 * sizeof(float), stream);
  hipMemsetAsync(Xsb, 0, M2 * sizeof(ushort_t), stream);
  hipMemsetAsync(X2, 0, M2 * sizeof(float), stream);
  hipMemsetAsync(X2b, 0, M2 * sizeof(ushort_t), stream);

  dim3 pgrid(16, 16);
  dim3 ggrid(16, 32);       // 64x64 tiles -> 512 blocks = 2/CU
  dim3 ggrid3(16, 32, 3);   // QKV: 1536 blocks = 6/CU
  dim3 agrid(BH_CNT, 16);   // fwd: (bh, y) balanced pairing
  dim3 bgrid(BH_CNT, 32);   // bwd: 1024 blocks = 4/CU, 34 units/CU constant

  // ---- stage 1 ----
  prep_w<<<pgrid, 256, 0, stream>>>(Wo, W0, W1);
  for (int t = 0; t < 3; t++) {
    gemm_mf<1, 1><<<ggrid, 256, 0, stream>>>(Xsb, nullptr, nullptr, W0, nullptr, nullptr,
                                             nullptr, T1, Rb, nullptr, nullptr,
                                             nullptr, nullptr, nullptr, 0.f);
    gemm_mf<2, 1><<<ggrid, 256, 0, stream>>>(Rb, nullptr, nullptr, W1, nullptr, nullptr,
                                             Xs, nullptr, Xsb, nullptr, nullptr,
                                             nullptr, nullptr, nullptr, LR_C);
  }
  prep_w<<<pgrid, 256, 0, stream>>>(Wq, W0, W3);
  prep_w<<<pgrid, 256, 0, stream>>>(Wk, W1, W4);
  prep_w<<<pgrid, 256, 0, stream>>>(Wv, W2, W5);

  // ---- stage 2 ----
  for (int t = 0; t < 3; t++) {
    gemm_mf<0, 1><<<ggrid3, 256, 0, stream>>>(X2b, nullptr, nullptr, W0, W1, W2,
                                              nullptr, nullptr, Qb, Kb, Vb,
                                              Qt, Kt, Vt, 0.f);
    fwd_fused<<<agrid, 256, 0, stream>>>(Qb, Kb, Vt, Xs, mS, lS, Gb, Gt, DvS);
    bwd_split<<<bgrid, 256, 0, stream>>>(Qb, Kb, Vb, Gb, Qt, Kt, Gt, mS, lS, DvS,
                                         GQb, GKb, GVb);
    gemm_mf<2, 3><<<ggrid, 256, 0, stream>>>(GQb, GKb, GVb, W3, W4, W5,
                                             X2, nullptr, X2b, nullptr, nullptr,
                                             nullptr, nullptr, nullptr, -LR_C);
  }
}

// Round 12
// 621.003 us; speedup vs baseline: 1.0702x; 1.0702x over previous
//
#include <hip/hip_runtime.h>
#include <hip/hip_bf16.h>

// Problem constants (B=2, S=1024, E=1024, H=16, D=64)
#define S_LEN 1024
#define E_DIM 1024
#define NH 16
#define HD 64
#define M_ROWS 2048   // B*S
#define BH_CNT 32     // B*NH

static constexpr float LR_C = 0.01f;
static constexpr float SC_C = 0.125f;                // 1/sqrt(64)
static constexpr float C2_C = 0.125f * 1.44269504f;  // SC * log2(e): log2-domain softmax

typedef unsigned short ushort_t;
typedef __attribute__((ext_vector_type(8))) __bf16 bf16x8;
typedef __attribute__((ext_vector_type(4))) float f32x4;

static __device__ inline ushort_t f2bu(float f) {
  __hip_bfloat16 h = __float2bfloat16(f);
  return *(ushort_t*)&h;
}
static __device__ inline bf16x8 ldg8(const ushort_t* p) { return *(const bf16x8*)p; }

// async global->LDS, 16B per lane; LDS dest = wave-uniform base + lane*16
static __device__ inline void async_cp16(const ushort_t* g, __bf16* lds_wave_base) {
  __builtin_amdgcn_global_load_lds((const __attribute__((address_space(1))) void*)g,
                                   (__attribute__((address_space(3))) void*)lds_wave_base,
                                   16, 0, 0);
}

// ---------------- weight prep: bf16 cast + bf16 transpose, 64x64 tiles ----------------
__global__ __launch_bounds__(256) void prep_w(const float* __restrict__ W,
                                              ushort_t* __restrict__ Wb,
                                              ushort_t* __restrict__ WTb) {
  __shared__ float ts[64][65];
  int bx = blockIdx.x * 64, by = blockIdx.y * 64;
  int t = threadIdx.x;
  int rr = t >> 6, cc = t & 63;
  #pragma unroll
  for (int p = 0; p < 16; p++) {
    int r = p * 4 + rr;
    float v = W[(size_t)(by + r) * E_DIM + bx + cc];
    ts[r][cc] = v;
    Wb[(size_t)(by + r) * E_DIM + bx + cc] = f2bu(v);
  }
  __syncthreads();
  #pragma unroll
  for (int p = 0; p < 16; p++) {
    int r = p * 4 + rr;
    WTb[(size_t)(bx + r) * E_DIM + by + cc] = f2bu(ts[cc][r]);
  }
}

// ---------------- bf16 MFMA GEMM, 64x64 tile, ASYNC global_load_lds staging ----------------
// Unpadded LDS (async requires contiguous wave writes); chunk-swizzled layout:
//   global chunk g of row R sits at chunk position (g - (R>>1)) & 3  ->
//   fragment ds_read_b128s are 2-way bank-aliased (free, m136) instead of 8-way.
// MODE 0: Cb_z = bf16(acc) + Ct_z transposed [bh][d][token]   [QKV proj]
// MODE 1: Cb0 = bf16(T - acc)                                 [stage-1 residual]
// MODE 2: Cf += alpha*acc (fp32) and Cb0 = bf16(Cf), NSEG K-segments [PC update]
template <int MODE, int NSEG>
__global__ __launch_bounds__(256) void gemm_mf(
    const ushort_t* __restrict__ A0, const ushort_t* __restrict__ A1, const ushort_t* __restrict__ A2,
    const ushort_t* __restrict__ B0, const ushort_t* __restrict__ B1, const ushort_t* __restrict__ B2,
    float* __restrict__ Cf, const float* __restrict__ T,
    ushort_t* __restrict__ Cb0, ushort_t* __restrict__ Cb1, ushort_t* __restrict__ Cb2,
    ushort_t* __restrict__ Ct0, ushort_t* __restrict__ Ct1, ushort_t* __restrict__ Ct2,
    float alpha) {
  const int K = 1024;
  __shared__ __bf16 As[64][32];   // unpadded: async staging target
  __shared__ __bf16 Bs[64][32];
  int tid = threadIdx.x;
  int m0 = blockIdx.y * 64, n0 = blockIdx.x * 64;

  const ushort_t* Bsel = B0;
  ushort_t* Cbz = Cb0;
  ushort_t* Ctz = Ct0;
  if (MODE == 0) {
    int z = blockIdx.z;
    Bsel = (z == 0) ? B0 : (z == 1) ? B1 : B2;
    Cbz = (z == 0) ? Cb0 : (z == 1) ? Cb1 : Cb2;
    Ctz = (z == 0) ? Ct0 : (z == 1) ? Ct1 : Ct2;
  }

  int lane = tid & 63, wave = tid >> 6;
  int wrow = wave >> 1, wcol = wave & 1;
  int fr = lane & 15, q = lane >> 4;

  // staging: wave w stages rows 16w..16w+15; lane l -> row 16w+(l>>2), swizzled chunk
  int srow = wave * 16 + (lane >> 2);
  int scg = ((lane & 3) + (srow >> 1)) & 3;          // global chunk this lane fetches
  int scol = scg * 8;                                 // element offset in row
  __bf16* ldsA = &As[wave * 16][0];                   // wave-uniform
  __bf16* ldsB = &Bs[wave * 16][0];

  // fragment read pointers (loop-invariant; swizzle-corrected)
  int rA0 = wrow * 32 + fr, rA1 = rA0 + 16;
  int rB0 = wcol * 32 + fr, rB1 = rB0 + 16;
  const bf16x8* pa0 = (const bf16x8*)&As[rA0][((q - (rA0 >> 1)) & 3) * 8];
  const bf16x8* pa1 = (const bf16x8*)&As[rA1][((q - (rA1 >> 1)) & 3) * 8];
  const bf16x8* pb0 = (const bf16x8*)&Bs[rB0][((q - (rB0 >> 1)) & 3) * 8];
  const bf16x8* pb1 = (const bf16x8*)&Bs[rB1][((q - (rB1 >> 1)) & 3) * 8];

  f32x4 acc[2][2] = {};

  #pragma unroll 1
  for (int seg = 0; seg < NSEG; seg++) {
    const ushort_t* Aseg = (seg == 0) ? A0 : (seg == 1) ? A1 : A2;
    const ushort_t* Bseg = (MODE == 0) ? Bsel : ((seg == 0) ? B0 : (seg == 1) ? B1 : B2);
    const ushort_t* ga = Aseg + (size_t)(m0 + srow) * K + scol;
    const ushort_t* gb = Bseg + (size_t)(n0 + srow) * K + scol;
    for (int k0 = 0; k0 < K; k0 += 32) {
      __syncthreads();                  // prior iteration's ds_reads complete
      async_cp16(ga + k0, ldsA);
      async_cp16(gb + k0, ldsB);
      __syncthreads();                  // drains vmcnt (async loads landed)
      bf16x8 a0 = *pa0, a1 = *pa1, b0 = *pb0, b1 = *pb1;
      acc[0][0] = __builtin_amdgcn_mfma_f32_16x16x32_bf16(a0, b0, acc[0][0], 0, 0, 0);
      acc[0][1] = __builtin_amdgcn_mfma_f32_16x16x32_bf16(a0, b1, acc[0][1], 0, 0, 0);
      acc[1][0] = __builtin_amdgcn_mfma_f32_16x16x32_bf16(a1, b0, acc[1][0], 0, 0, 0);
      acc[1][1] = __builtin_amdgcn_mfma_f32_16x16x32_bf16(a1, b1, acc[1][1], 0, 0, 0);
    }
  }

  // C/D layout: col = lane&15, row = (lane>>4)*4 + reg
  #pragma unroll
  for (int mi = 0; mi < 2; mi++)
    #pragma unroll
    for (int ni = 0; ni < 2; ni++) {
      int col = n0 + wcol * 32 + ni * 16 + fr;
      int row0 = m0 + wrow * 32 + mi * 16 + q * 4;
      ushort_t pk[4];
      #pragma unroll
      for (int r = 0; r < 4; r++) {
        size_t idx = (size_t)(row0 + r) * E_DIM + col;
        float v = acc[mi][ni][r];
        if (MODE == 0) {
          ushort_t bu = f2bu(v);
          pk[r] = bu;
          Cbz[idx] = bu;
        } else if (MODE == 1) {
          Cb0[idx] = f2bu(T[idx] - v);
        } else {
          float nv = Cf[idx] + alpha * v;
          Cf[idx] = nv;
          Cb0[idx] = f2bu(nv);
        }
      }
      if (MODE == 0) {
        int hh = col >> 6, dd = col & 63;
        int bb = row0 >> 10, ss = row0 & 1023;
        *(uint2*)(Ctz + ((size_t)((bb * NH + hh) * HD + dd)) * S_LEN + ss) = *(uint2*)pk;
      }
    }
}

// ====================== MFMA attention, LDS-staged ======================

// ---- fused fwd: single-pass flash, log2-domain online softmax; emits m(log2-scaled),
//      1/l, g=O-Xs (bf16 + transposed), Dv. grid (bh=32, y=16), balanced pairing. ----
__global__ __launch_bounds__(256) void fwd_fused(const ushort_t* __restrict__ Qg,
                                                 const ushort_t* __restrict__ Kg,
                                                 const ushort_t* __restrict__ Vt,
                                                 const float* __restrict__ Xs,
                                                 float* __restrict__ mbuf,
                                                 float* __restrict__ lbuf,
                                                 ushort_t* __restrict__ Gb,
                                                 ushort_t* __restrict__ Gt,
                                                 float* __restrict__ Dv) {
  int bh = blockIdx.x, y = blockIdx.y;
  int it = (y < 8) ? (15 - y) : (y - 8);
  int b = bh >> 4, h = bh & 15;
  int tid = threadIdx.x, lane = tid & 63, wv = tid >> 6;
  int fr = lane & 15, q = lane >> 4;
  int i0 = it * 64, band = wv * 16;
  __shared__ ushort_t Kts[64][72];  // [j][d]
  __shared__ ushort_t Vts[64][72];  // [d][j]
  __shared__ ushort_t Ps[64][72];   // [i][j] wave-private bands

  const ushort_t* Qrow = Qg + (size_t)(b * S_LEN + i0 + band + fr) * E_DIM + h * HD;
  bf16x8 aq0 = ldg8(Qrow + q * 8);
  bf16x8 aq1 = ldg8(Qrow + 32 + q * 8);

  float m[4], l[4];
  #pragma unroll
  for (int r = 0; r < 4; r++) { m[r] = -1e30f; l[r] = 0.f; }
  f32x4 oacc[4] = {};

  #pragma unroll 1
  for (int jt = 0; jt <= it; jt++) {
    int j0 = jt * 64;
    __syncthreads();
    #pragma unroll
    for (int t = 0; t < 2; t++) {
      int u = tid + 256 * t;
      int r = u >> 3, c8 = (u & 7) * 8;
      *(uint4*)&Kts[r][c8] = *(const uint4*)(Kg + (size_t)(b * S_LEN + j0 + r) * E_DIM + h * HD + c8);
      *(uint4*)&Vts[r][c8] = *(const uint4*)(Vt + (size_t)(bh * HD + r) * S_LEN + j0 + c8);
    }
    __syncthreads();
    f32x4 sA[4];
    #pragma unroll
    for (int nc = 0; nc < 4; nc++) {
      bf16x8 bk0 = *(const bf16x8*)&Kts[nc * 16 + fr][q * 8];
      bf16x8 bk1 = *(const bf16x8*)&Kts[nc * 16 + fr][32 + q * 8];
      f32x4 z = {};
      z = __builtin_amdgcn_mfma_f32_16x16x32_bf16(aq0, bk0, z, 0, 0, 0);
      sA[nc] = __builtin_amdgcn_mfma_f32_16x16x32_bf16(aq1, bk1, z, 0, 0, 0);
    }
    float sv[4][4];
    #pragma unroll
    for (int nc = 0; nc < 4; nc++)
      #pragma unroll
      for (int r = 0; r < 4; r++) {
        int row = i0 + band + q * 4 + r;
        int col = j0 + nc * 16 + fr;
        sv[nc][r] = (col <= row) ? sA[nc][r] * C2_C : -1e30f;  // log2 domain
      }
    #pragma unroll
    for (int r = 0; r < 4; r++) {
      float mx = fmaxf(fmaxf(sv[0][r], sv[1][r]), fmaxf(sv[2][r], sv[3][r]));
      #pragma unroll
      for (int off = 1; off < 16; off <<= 1) mx = fmaxf(mx, __shfl_xor(mx, off, 64));
      float mn = fmaxf(m[r], mx);
      float alpha = exp2f(m[r] - mn);
      float ps = 0.f;
      #pragma unroll
      for (int nc = 0; nc < 4; nc++) {
        float p = exp2f(sv[nc][r] - mn);
        Ps[band + q * 4 + r][nc * 16 + fr] = f2bu(p);
        ps += p;
      }
      #pragma unroll
      for (int off = 1; off < 16; off <<= 1) ps += __shfl_xor(ps, off, 64);
      l[r] = l[r] * alpha + ps;
      m[r] = mn;
      #pragma unroll
      for (int nc = 0; nc < 4; nc++) oacc[nc][r] *= alpha;
    }
    bf16x8 ap0 = *(const bf16x8*)&Ps[band + fr][q * 8];
    bf16x8 ap1 = *(const bf16x8*)&Ps[band + fr][32 + q * 8];
    #pragma unroll
    for (int nc = 0; nc < 4; nc++) {
      bf16x8 bv0 = *(const bf16x8*)&Vts[nc * 16 + fr][q * 8];
      bf16x8 bv1 = *(const bf16x8*)&Vts[nc * 16 + fr][32 + q * 8];
      oacc[nc] = __builtin_amdgcn_mfma_f32_16x16x32_bf16(ap0, bv0, oacc[nc], 0, 0, 0);
      oacc[nc] = __builtin_amdgcn_mfma_f32_16x16x32_bf16(ap1, bv1, oacc[nc], 0, 0, 0);
    }
  }
  // epilogue: g = O - Xs (bf16 normal + transposed), Dv partials
  float linv[4];
  #pragma unroll
  for (int r = 0; r < 4; r++) linv[r] = 1.0f / l[r];
  float dpart[4] = {};
  #pragma unroll
  for (int nc = 0; nc < 4; nc++) {
    ushort_t pg[4];
    #pragma unroll
    for (int r = 0; r < 4; r++) {
      int row = i0 + band + q * 4 + r;
      size_t gi = (size_t)(b * S_LEN + row) * E_DIM + h * HD + nc * 16 + fr;
      float o = oacc[nc][r] * linv[r];
      float g = o - Xs[gi];
      ushort_t bu = f2bu(g);
      Gb[gi] = bu;
      pg[r] = bu;
      dpart[r] += g * o;
    }
    int d = nc * 16 + fr;
    int s0 = i0 + band + q * 4;
    *(uint2*)(Gt + ((size_t)bh * HD + d) * S_LEN + s0) = *(uint2*)pg;
  }
  #pragma unroll
  for (int r = 0; r < 4; r++) {
    #pragma unroll
    for (int off = 1; off < 16; off <<= 1) dpart[r] += __shfl_xor(dpart[r], off, 64);
  }
  if (fr == 0) {
    #pragma unroll
    for (int r = 0; r < 4; r++) {
      size_t sid = (size_t)bh * S_LEN + i0 + band + q * 4 + r;
      mbuf[sid] = m[r];      // log2-scaled
      lbuf[sid] = linv[r];
      Dv[sid] = dpart[r];
    }
  }
}

// ---- merged backward (R10-proven): block (bh, y) does dq for i-tile y (y+1 units)
//      then dk/dv for j-tile y (16-y units) = exactly 17 units per block. ----
__global__ __launch_bounds__(256) void bwd_fused(const ushort_t* __restrict__ Qg,
                                                 const ushort_t* __restrict__ Kg,
                                                 const ushort_t* __restrict__ Vg,
                                                 const ushort_t* __restrict__ Gg,
                                                 const ushort_t* __restrict__ Qt,
                                                 const ushort_t* __restrict__ Kt,
                                                 const ushort_t* __restrict__ Gt,
                                                 const float* __restrict__ mbuf,
                                                 const float* __restrict__ lbuf,
                                                 const float* __restrict__ Dv,
                                                 ushort_t* __restrict__ GQ,
                                                 ushort_t* __restrict__ GK,
                                                 ushort_t* __restrict__ GV) {
  int bh = blockIdx.x, y = blockIdx.y;
  int b = bh >> 4, h = bh & 15;
  int tid = threadIdx.x, lane = tid & 63, wv = tid >> 6;
  int fr = lane & 15, q = lane >> 4;
  int band = wv * 16;
  __shared__ ushort_t smem[6][64][72];  // aliased across phases

  // ================= phase A: dq for i-tile y =================
  {
    ushort_t (*Kts)[72] = smem[0];  // [j][d]
    ushort_t (*Vts)[72] = smem[1];  // [j][d]
    ushort_t (*Ktt)[72] = smem[2];  // [d][j]
    ushort_t (*dSs)[72] = smem[3];
    int it = y, i0 = it * 64;

    const ushort_t* Qrow = Qg + (size_t)(b * S_LEN + i0 + band + fr) * E_DIM + h * HD;
    const ushort_t* Grow = Gg + (size_t)(b * S_LEN + i0 + band + fr) * E_DIM + h * HD;
    bf16x8 aq0 = ldg8(Qrow + q * 8), aq1 = ldg8(Qrow + 32 + q * 8);
    bf16x8 ag0 = ldg8(Grow + q * 8), ag1 = ldg8(Grow + 32 + q * 8);

    float mrow[4], linv[4], Dr[4];
    #pragma unroll
    for (int r = 0; r < 4; r++) {
      size_t sid = (size_t)bh * S_LEN + i0 + band + q * 4 + r;
      mrow[r] = mbuf[sid]; linv[r] = lbuf[sid]; Dr[r] = Dv[sid];
    }
    f32x4 dqacc[4] = {};

    #pragma unroll 1
    for (int jt = 0; jt <= it; jt++) {
      int j0 = jt * 64;
      __syncthreads();
      #pragma unroll
      for (int t = 0; t < 2; t++) {
        int u = tid + 256 * t;
        int r = u >> 3, c8 = (u & 7) * 8;
        *(uint4*)&Kts[r][c8] = *(const uint4*)(Kg + (size_t)(b * S_LEN + j0 + r) * E_DIM + h * HD + c8);
        *(uint4*)&Vts[r][c8] = *(const uint4*)(Vg + (size_t)(b * S_LEN + j0 + r) * E_DIM + h * HD + c8);
        *(uint4*)&Ktt[r][c8] = *(const uint4*)(Kt + (size_t)(bh * HD + r) * S_LEN + j0 + c8);
      }
      __syncthreads();
      f32x4 sA[4], dpA[4];
      #pragma unroll
      for (int nc = 0; nc < 4; nc++) {
        bf16x8 bk0 = *(const bf16x8*)&Kts[nc * 16 + fr][q * 8];
        bf16x8 bk1 = *(const bf16x8*)&Kts[nc * 16 + fr][32 + q * 8];
        bf16x8 bv0 = *(const bf16x8*)&Vts[nc * 16 + fr][q * 8];
        bf16x8 bv1 = *(const bf16x8*)&Vts[nc * 16 + fr][32 + q * 8];
        f32x4 z = {};
        z = __builtin_amdgcn_mfma_f32_16x16x32_bf16(aq0, bk0, z, 0, 0, 0);
        sA[nc] = __builtin_amdgcn_mfma_f32_16x16x32_bf16(aq1, bk1, z, 0, 0, 0);
        f32x4 z2 = {};
        z2 = __builtin_amdgcn_mfma_f32_16x16x32_bf16(ag0, bv0, z2, 0, 0, 0);
        dpA[nc] = __builtin_amdgcn_mfma_f32_16x16x32_bf16(ag1, bv1, z2, 0, 0, 0);
      }
      #pragma unroll
      for (int nc = 0; nc < 4; nc++)
        #pragma unroll
        for (int r = 0; r < 4; r++) {
          int row = i0 + band + q * 4 + r;
          int col = j0 + nc * 16 + fr;
          float ds = 0.f;
          if (col <= row) {
            float P = exp2f(fmaf(sA[nc][r], C2_C, -mrow[r])) * linv[r];
            ds = P * (dpA[nc][r] - Dr[r]) * SC_C;
          }
          dSs[band + q * 4 + r][nc * 16 + fr] = f2bu(ds);  // wave-private
        }
      bf16x8 ad0 = *(const bf16x8*)&dSs[band + fr][q * 8];
      bf16x8 ad1 = *(const bf16x8*)&dSs[band + fr][32 + q * 8];
      #pragma unroll
      for (int nc = 0; nc < 4; nc++) {
        bf16x8 bt0 = *(const bf16x8*)&Ktt[nc * 16 + fr][q * 8];
        bf16x8 bt1 = *(const bf16x8*)&Ktt[nc * 16 + fr][32 + q * 8];
        dqacc[nc] = __builtin_amdgcn_mfma_f32_16x16x32_bf16(ad0, bt0, dqacc[nc], 0, 0, 0);
        dqacc[nc] = __builtin_amdgcn_mfma_f32_16x16x32_bf16(ad1, bt1, dqacc[nc], 0, 0, 0);
      }
    }
    #pragma unroll
    for (int nc = 0; nc < 4; nc++)
      #pragma unroll
      for (int r = 0; r < 4; r++) {
        int row = i0 + band + q * 4 + r;
        size_t gi = (size_t)(b * S_LEN + row) * E_DIM + h * HD + nc * 16 + fr;
        GQ[gi] = f2bu(dqacc[nc][r]);
      }
  }

  // ================= phase B: dk/dv for j-tile y =================
  {
    ushort_t (*Qs_)[72] = smem[0];  // [i][d]
    ushort_t (*Gs_)[72] = smem[1];  // [i][d]
    ushort_t (*Qtt)[72] = smem[2];  // [d][i]
    ushort_t (*Gtt)[72] = smem[3];  // [d][i]
    ushort_t (*PT)[72]  = smem[4];  // [j][i]
    ushort_t (*dST)[72] = smem[5];  // [j][i]
    int jt = y, j0 = jt * 64;

    const ushort_t* Krow = Kg + (size_t)(b * S_LEN + j0 + band + fr) * E_DIM + h * HD;
    const ushort_t* Vrow = Vg + (size_t)(b * S_LEN + j0 + band + fr) * E_DIM + h * HD;
    bf16x8 ak0 = ldg8(Krow + q * 8), ak1 = ldg8(Krow + 32 + q * 8);
    bf16x8 av0 = ldg8(Vrow + q * 8), av1 = ldg8(Vrow + 32 + q * 8);

    f32x4 dkacc[4] = {}, dvacc[4] = {};

    #pragma unroll 1
    for (int i_t = jt; i_t < 16; i_t++) {
      int i0 = i_t * 64;
      __syncthreads();  // also protects phase-A's last LDS reads on first iteration
      #pragma unroll
      for (int t = 0; t < 2; t++) {
        int u = tid + 256 * t;
        int r = u >> 3, c8 = (u & 7) * 8;
        *(uint4*)&Qs_[r][c8] = *(const uint4*)(Qg + (size_t)(b * S_LEN + i0 + r) * E_DIM + h * HD + c8);
        *(uint4*)&Gs_[r][c8] = *(const uint4*)(Gg + (size_t)(b * S_LEN + i0 + r) * E_DIM + h * HD + c8);
        *(uint4*)&Qtt[r][c8] = *(const uint4*)(Qt + (size_t)(bh * HD + r) * S_LEN + i0 + c8);
        *(uint4*)&Gtt[r][c8] = *(const uint4*)(Gt + (size_t)(bh * HD + r) * S_LEN + i0 + c8);
      }
      __syncthreads();
      float mc[4], lc[4], Dc[4];
      #pragma unroll
      for (int nc = 0; nc < 4; nc++) {
        size_t sid = (size_t)bh * S_LEN + i0 + nc * 16 + fr;
        mc[nc] = mbuf[sid]; lc[nc] = lbuf[sid]; Dc[nc] = Dv[sid];
      }
      f32x4 stA[4], dptA[4];
      #pragma unroll
      for (int nc = 0; nc < 4; nc++) {
        bf16x8 bq0 = *(const bf16x8*)&Qs_[nc * 16 + fr][q * 8];
        bf16x8 bq1 = *(const bf16x8*)&Qs_[nc * 16 + fr][32 + q * 8];
        bf16x8 bg0 = *(const bf16x8*)&Gs_[nc * 16 + fr][q * 8];
        bf16x8 bg1 = *(const bf16x8*)&Gs_[nc * 16 + fr][32 + q * 8];
        f32x4 z = {};
        z = __builtin_amdgcn_mfma_f32_16x16x32_bf16(ak0, bq0, z, 0, 0, 0);
        stA[nc] = __builtin_amdgcn_mfma_f32_16x16x32_bf16(ak1, bq1, z, 0, 0, 0);
        f32x4 z2 = {};
        z2 = __builtin_amdgcn_mfma_f32_16x16x32_bf16(av0, bg0, z2, 0, 0, 0);
        dptA[nc] = __builtin_amdgcn_mfma_f32_16x16x32_bf16(av1, bg1, z2, 0, 0, 0);
      }
      #pragma unroll
      for (int nc = 0; nc < 4; nc++)
        #pragma unroll
        for (int r = 0; r < 4; r++) {
          int jrow = j0 + band + q * 4 + r;
          int icol = i0 + nc * 16 + fr;
          float P = 0.f, ds = 0.f;
          if (icol >= jrow) {
            P = exp2f(fmaf(stA[nc][r], C2_C, -mc[nc])) * lc[nc];
            ds = P * (dptA[nc][r] - Dc[nc]) * SC_C;
          }
          PT[band + q * 4 + r][nc * 16 + fr] = f2bu(P);   // wave-private
          dST[band + q * 4 + r][nc * 16 + fr] = f2bu(ds);
        }
      bf16x8 ap0 = *(const bf16x8*)&PT[band + fr][q * 8];
      bf16x8 ap1 = *(const bf16x8*)&PT[band + fr][32 + q * 8];
      bf16x8 ad0 = *(const bf16x8*)&dST[band + fr][q * 8];
      bf16x8 ad1 = *(const bf16x8*)&dST[band + fr][32 + q * 8];
      #pragma unroll
      for (int nc = 0; nc < 4; nc++) {
        bf16x8 bg0 = *(const bf16x8*)&Gtt[nc * 16 + fr][q * 8];
        bf16x8 bg1 = *(const bf16x8*)&Gtt[nc * 16 + fr][32 + q * 8];
        bf16x8 bq0 = *(const bf16x8*)&Qtt[nc * 16 + fr][q * 8];
        bf16x8 bq1 = *(const bf16x8*)&Qtt[nc * 16 + fr][32 + q * 8];
        dvacc[nc] = __builtin_amdgcn_mfma_f32_16x16x32_bf16(ap0, bg0, dvacc[nc], 0, 0, 0);
        dvacc[nc] = __builtin_amdgcn_mfma_f32_16x16x32_bf16(ap1, bg1, dvacc[nc], 0, 0, 0);
        dkacc[nc] = __builtin_amdgcn_mfma_f32_16x16x32_bf16(ad0, bq0, dkacc[nc], 0, 0, 0);
        dkacc[nc] = __builtin_amdgcn_mfma_f32_16x16x32_bf16(ad1, bq1, dkacc[nc], 0, 0, 0);
      }
    }
    #pragma unroll
    for (int nc = 0; nc < 4; nc++)
      #pragma unroll
      for (int r = 0; r < 4; r++) {
        int jrow = j0 + band + q * 4 + r;
        size_t gi = (size_t)(b * S_LEN + jrow) * E_DIM + h * HD + nc * 16 + fr;
        GK[gi] = f2bu(dkacc[nc][r]);
        GV[gi] = f2bu(dvacc[nc][r]);
      }
  }
}

// ---------------- launch ----------------
extern "C" void kernel_launch(void* const* d_in, const int* in_sizes, int n_in,
                              void* d_out, int out_size, void* d_ws, size_t ws_size,
                              hipStream_t stream) {
  const float* T1 = (const float*)d_in[0];
  const float* Wq = (const float*)d_in[1];
  const float* Wk = (const float*)d_in[2];
  const float* Wv = (const float*)d_in[3];
  const float* Wo = (const float*)d_in[4];

  const size_t M2 = 2097152;   // 2048*1024
  const size_t M1 = 1048576;
  float* w = (float*)d_ws;
  float* Xs = w;                       // 8 MB fp32 target
  float* mS = Xs + M2;                 // 64K f32
  float* lS = mS + 65536;
  float* DvS = lS + 65536;
  ushort_t* u = (ushort_t*)(DvS + 65536);
  ushort_t* W0 = u;          ushort_t* W1 = W0 + M1;  ushort_t* W2 = W1 + M1;
  ushort_t* W3 = W2 + M1;    ushort_t* W4 = W3 + M1;  ushort_t* W5 = W4 + M1;
  ushort_t* Qb = W5 + M1;    ushort_t* Kb = Qb + M2;  ushort_t* Vb = Kb + M2;
  ushort_t* Qt = Vb + M2;    ushort_t* Kt = Qt + M2;  ushort_t* Vt = Kt + M2;
  ushort_t* Gt = Vt + M2;
  ushort_t* Gb = Gt + M2;
  ushort_t* GQb = Gb + M2;   ushort_t* GKb = GQb + M2; ushort_t* GVb = GKb + M2;
  ushort_t* X2b = GVb + M2;
  ushort_t* Rb = GQb;        // stage-1 aliases
  ushort_t* Xsb = GKb;
  float* X2 = (float*)d_out;

  hipMemsetAsync(Xs, 0, M2 * sizeof(float), stream);
  hipMemsetAsync(Xsb, 0, M2 * sizeof(ushort_t), stream);
  hipMemsetAsync(X2, 0, M2 * sizeof(float), stream);
  hipMemsetAsync(X2b, 0, M2 * sizeof(ushort_t), stream);

  dim3 pgrid(16, 16);
  dim3 ggrid(16, 32);       // 64x64 tiles -> 512 blocks = 2/CU
  dim3 ggrid3(16, 32, 3);   // QKV: 1536 blocks = 6/CU
  dim3 agrid(BH_CNT, 16);   // attention: (bh, y) balanced mapping

  // ---- stage 1 ----
  prep_w<<<pgrid, 256, 0, stream>>>(Wo, W0, W1);
  for (int t = 0; t < 3; t++) {
    gemm_mf<1, 1><<<ggrid, 256, 0, stream>>>(Xsb, nullptr, nullptr, W0, nullptr, nullptr,
                                             nullptr, T1, Rb, nullptr, nullptr,
                                             nullptr, nullptr, nullptr, 0.f);
    gemm_mf<2, 1><<<ggrid, 256, 0, stream>>>(Rb, nullptr, nullptr, W1, nullptr, nullptr,
                                             Xs, nullptr, Xsb, nullptr, nullptr,
                                             nullptr, nullptr, nullptr, LR_C);
  }
  prep_w<<<pgrid, 256, 0, stream>>>(Wq, W0, W3);
  prep_w<<<pgrid, 256, 0, stream>>>(Wk, W1, W4);
  prep_w<<<pgrid, 256, 0, stream>>>(Wv, W2, W5);

  // ---- stage 2 ----
  for (int t = 0; t < 3; t++) {
    gemm_mf<0, 1><<<ggrid3, 256, 0, stream>>>(X2b, nullptr, nullptr, W0, W1, W2,
                                              nullptr, nullptr, Qb, Kb, Vb,
                                              Qt, Kt, Vt, 0.f);
    fwd_fused<<<agrid, 256, 0, stream>>>(Qb, Kb, Vt, Xs, mS, lS, Gb, Gt, DvS);
    bwd_fused<<<agrid, 256, 0, stream>>>(Qb, Kb, Vb, Gb, Qt, Kt, Gt, mS, lS, DvS,
                                         GQb, GKb, GVb);
    gemm_mf<2, 3><<<ggrid, 256, 0, stream>>>(GQb, GKb, GVb, W3, W4, W5,
                                             X2, nullptr, X2b, nullptr, nullptr,
                                             nullptr, nullptr, nullptr, -LR_C);
  }
}

// Round 13
// 572.549 us; speedup vs baseline: 1.1608x; 1.0846x over previous
//
#include <hip/hip_runtime.h>
#include <hip/hip_bf16.h>
#include <math.h>

// Problem constants (B=2, S=1024, E=1024, H=16, D=64)
#define S_LEN 1024
#define E_DIM 1024
#define NH 16
#define HD 64
#define M_ROWS 2048   // B*S
#define BH_CNT 32     // B*NH

static constexpr float LR_C = 0.01f;
static constexpr float SC_C = 0.125f;                // 1/sqrt(64)
static constexpr float C2_C = 0.125f * 1.44269504f;  // SC * log2(e): log2-domain softmax

typedef unsigned short ushort_t;
typedef __attribute__((ext_vector_type(8))) __bf16 bf16x8;
typedef __attribute__((ext_vector_type(4))) float f32x4;

static __device__ inline ushort_t f2bu(float f) {
  __hip_bfloat16 h = __float2bfloat16(f);
  return *(ushort_t*)&h;
}
static __device__ inline bf16x8 ldg8(const ushort_t* p) { return *(const bf16x8*)p; }

// async global->LDS, 16B per lane; LDS dest = wave-uniform base + lane*16
static __device__ inline void async_cp16(const ushort_t* g, __bf16* lds_wave_base) {
  __builtin_amdgcn_global_load_lds((const __attribute__((address_space(1))) void*)g,
                                   (__attribute__((address_space(3))) void*)lds_wave_base,
                                   16, 0, 0);
}

// ---------------- weight prep: bf16 cast + bf16 transpose, 64x64 tiles ----------------
__global__ __launch_bounds__(256) void prep_w(const float* __restrict__ W,
                                              ushort_t* __restrict__ Wb,
                                              ushort_t* __restrict__ WTb) {
  __shared__ float ts[64][65];
  int bx = blockIdx.x * 64, by = blockIdx.y * 64;
  int t = threadIdx.x;
  int rr = t >> 6, cc = t & 63;
  #pragma unroll
  for (int p = 0; p < 16; p++) {
    int r = p * 4 + rr;
    float v = W[(size_t)(by + r) * E_DIM + bx + cc];
    ts[r][cc] = v;
    Wb[(size_t)(by + r) * E_DIM + bx + cc] = f2bu(v);
  }
  __syncthreads();
  #pragma unroll
  for (int p = 0; p < 16; p++) {
    int r = p * 4 + rr;
    WTb[(size_t)(bx + r) * E_DIM + by + cc] = f2bu(ts[cc][r]);
  }
}

// ---------------- fp32 -> bf16 cast (float4-wide) ----------------
__global__ __launch_bounds__(256) void k_cast(const float* __restrict__ in,
                                              ushort_t* __restrict__ out, int n4) {
  int i = blockIdx.x * 256 + threadIdx.x;
  if (i < n4) {
    float4 v = ((const float4*)in)[i];
    ushort_t p[4] = {f2bu(v.x), f2bu(v.y), f2bu(v.z), f2bu(v.w)};
    *(uint2*)(out + (size_t)i * 4) = *(uint2*)p;
  }
}

// ---------------- N = 3LR*I - 3LR^2*M + LR^3*M2  (bf16 out) ----------------
__global__ __launch_bounds__(256) void k_formN(const float* __restrict__ Mf,
                                               const float* __restrict__ M2f,
                                               ushort_t* __restrict__ Nb) {
  int idx = blockIdx.x * 256 + threadIdx.x;   // 1M elements
  int i = idx >> 10, j = idx & 1023;
  float v = -3.f * LR_C * LR_C * Mf[idx] + LR_C * LR_C * LR_C * M2f[idx];
  if (i == j) v += 3.f * LR_C;
  Nb[idx] = f2bu(v);
}

// ---------------- bf16 MFMA GEMM, 64x64 tile, ASYNC global_load_lds staging ----------------
// Chunk-swizzled unpadded LDS (2-way banks on b128 reads).
// MODE 0: Cb_z = bf16(acc) + Ct_z per-head transposed [bh][d][token], Qt/Kt pre-scaled by SC
// MODE 2: Cf += alpha*acc (fp32) and Cb0 = bf16(Cf), NSEG K-segments
// MODE 3: Cf = acc (fp32 only)
// MODE 4: Cf = acc and Cb0 = bf16(acc)
// MODE 5: Cb0 = bf16(acc)
template <int MODE, int NSEG>
__global__ __launch_bounds__(256) void gemm_mf(
    const ushort_t* __restrict__ A0, const ushort_t* __restrict__ A1, const ushort_t* __restrict__ A2,
    const ushort_t* __restrict__ B0, const ushort_t* __restrict__ B1, const ushort_t* __restrict__ B2,
    float* __restrict__ Cf,
    ushort_t* __restrict__ Cb0, ushort_t* __restrict__ Cb1, ushort_t* __restrict__ Cb2,
    ushort_t* __restrict__ Ct0, ushort_t* __restrict__ Ct1, ushort_t* __restrict__ Ct2,
    float alpha) {
  const int K = 1024;
  __shared__ __bf16 As[64][32];
  __shared__ __bf16 Bs[64][32];
  int tid = threadIdx.x;
  int m0 = blockIdx.y * 64, n0 = blockIdx.x * 64;

  const ushort_t* Bsel = B0;
  ushort_t* Cbz = Cb0;
  ushort_t* Ctz = Ct0;
  float tsc = 1.0f;
  if (MODE == 0) {
    int z = blockIdx.z;
    Bsel = (z == 0) ? B0 : (z == 1) ? B1 : B2;
    Cbz = (z == 0) ? Cb0 : (z == 1) ? Cb1 : Cb2;
    Ctz = (z == 0) ? Ct0 : (z == 1) ? Ct1 : Ct2;
    tsc = (z == 2) ? 1.0f : SC_C;   // Qt/Kt carry the 1/sqrt(d) factor
  }

  int lane = tid & 63, wave = tid >> 6;
  int wrow = wave >> 1, wcol = wave & 1;
  int fr = lane & 15, q = lane >> 4;

  int srow = wave * 16 + (lane >> 2);
  int scg = ((lane & 3) + (srow >> 1)) & 3;
  int scol = scg * 8;
  __bf16* ldsA = &As[wave * 16][0];
  __bf16* ldsB = &Bs[wave * 16][0];

  int rA0 = wrow * 32 + fr, rA1 = rA0 + 16;
  int rB0 = wcol * 32 + fr, rB1 = rB0 + 16;
  const bf16x8* pa0 = (const bf16x8*)&As[rA0][((q - (rA0 >> 1)) & 3) * 8];
  const bf16x8* pa1 = (const bf16x8*)&As[rA1][((q - (rA1 >> 1)) & 3) * 8];
  const bf16x8* pb0 = (const bf16x8*)&Bs[rB0][((q - (rB0 >> 1)) & 3) * 8];
  const bf16x8* pb1 = (const bf16x8*)&Bs[rB1][((q - (rB1 >> 1)) & 3) * 8];

  f32x4 acc[2][2] = {};

  #pragma unroll 1
  for (int seg = 0; seg < NSEG; seg++) {
    const ushort_t* Aseg = (seg == 0) ? A0 : (seg == 1) ? A1 : A2;
    const ushort_t* Bseg = (MODE == 0) ? Bsel : ((seg == 0) ? B0 : (seg == 1) ? B1 : B2);
    const ushort_t* ga = Aseg + (size_t)(m0 + srow) * K + scol;
    const ushort_t* gb = Bseg + (size_t)(n0 + srow) * K + scol;
    for (int k0 = 0; k0 < K; k0 += 32) {
      __syncthreads();
      async_cp16(ga + k0, ldsA);
      async_cp16(gb + k0, ldsB);
      __syncthreads();
      bf16x8 a0 = *pa0, a1 = *pa1, b0 = *pb0, b1 = *pb1;
      acc[0][0] = __builtin_amdgcn_mfma_f32_16x16x32_bf16(a0, b0, acc[0][0], 0, 0, 0);
      acc[0][1] = __builtin_amdgcn_mfma_f32_16x16x32_bf16(a0, b1, acc[0][1], 0, 0, 0);
      acc[1][0] = __builtin_amdgcn_mfma_f32_16x16x32_bf16(a1, b0, acc[1][0], 0, 0, 0);
      acc[1][1] = __builtin_amdgcn_mfma_f32_16x16x32_bf16(a1, b1, acc[1][1], 0, 0, 0);
    }
  }

  // C/D layout: col = lane&15, row = (lane>>4)*4 + reg
  #pragma unroll
  for (int mi = 0; mi < 2; mi++)
    #pragma unroll
    for (int ni = 0; ni < 2; ni++) {
      int col = n0 + wcol * 32 + ni * 16 + fr;
      int row0 = m0 + wrow * 32 + mi * 16 + q * 4;
      ushort_t pk[4];
      #pragma unroll
      for (int r = 0; r < 4; r++) {
        size_t idx = (size_t)(row0 + r) * E_DIM + col;
        float v = acc[mi][ni][r];
        if (MODE == 0) {
          Cbz[idx] = f2bu(v);
          pk[r] = f2bu(v * tsc);
        } else if (MODE == 2) {
          float nv = Cf[idx] + alpha * v;
          Cf[idx] = nv;
          Cb0[idx] = f2bu(nv);
        } else if (MODE == 3) {
          Cf[idx] = v;
        } else if (MODE == 4) {
          Cf[idx] = v;
          Cb0[idx] = f2bu(v);
        } else {  // MODE 5
          Cb0[idx] = f2bu(v);
        }
      }
      if (MODE == 0) {
        int hh = col >> 6, dd = col & 63;
        int bb = row0 >> 10, ss = row0 & 1023;
        *(uint2*)(Ctz + ((size_t)((bb * NH + hh) * HD + dd)) * S_LEN + ss) = *(uint2*)pk;
      }
    }
}

// ====================== MFMA attention, LDS-staged ======================

// ---- fused fwd: single-pass flash, log2-domain online softmax; emits m' = m + log2(l),
//      g=O-Xs (bf16 + transposed), Dv. grid (bh=32, y=16), balanced pairing. ----
__global__ __launch_bounds__(256) void fwd_fused(const ushort_t* __restrict__ Qg,
                                                 const ushort_t* __restrict__ Kg,
                                                 const ushort_t* __restrict__ Vt,
                                                 const float* __restrict__ Xs,
                                                 float* __restrict__ mbuf,
                                                 ushort_t* __restrict__ Gb,
                                                 ushort_t* __restrict__ Gt,
                                                 float* __restrict__ Dv) {
  int bh = blockIdx.x, y = blockIdx.y;
  int it = (y < 8) ? (15 - y) : (y - 8);
  int b = bh >> 4, h = bh & 15;
  int tid = threadIdx.x, lane = tid & 63, wv = tid >> 6;
  int fr = lane & 15, q = lane >> 4;
  int i0 = it * 64, band = wv * 16;
  __shared__ ushort_t Kts[64][72];  // [j][d]
  __shared__ ushort_t Vts[64][72];  // [d][j]
  __shared__ ushort_t Ps[64][72];   // [i][j] wave-private bands

  const ushort_t* Qrow = Qg + (size_t)(b * S_LEN + i0 + band + fr) * E_DIM + h * HD;
  bf16x8 aq0 = ldg8(Qrow + q * 8);
  bf16x8 aq1 = ldg8(Qrow + 32 + q * 8);

  float m[4], l[4];
  #pragma unroll
  for (int r = 0; r < 4; r++) { m[r] = -1e30f; l[r] = 0.f; }
  f32x4 oacc[4] = {};

  #pragma unroll 1
  for (int jt = 0; jt <= it; jt++) {
    int j0 = jt * 64;
    __syncthreads();
    #pragma unroll
    for (int t = 0; t < 2; t++) {
      int u = tid + 256 * t;
      int r = u >> 3, c8 = (u & 7) * 8;
      *(uint4*)&Kts[r][c8] = *(const uint4*)(Kg + (size_t)(b * S_LEN + j0 + r) * E_DIM + h * HD + c8);
      *(uint4*)&Vts[r][c8] = *(const uint4*)(Vt + (size_t)(bh * HD + r) * S_LEN + j0 + c8);
    }
    __syncthreads();
    f32x4 sA[4];
    #pragma unroll
    for (int nc = 0; nc < 4; nc++) {
      bf16x8 bk0 = *(const bf16x8*)&Kts[nc * 16 + fr][q * 8];
      bf16x8 bk1 = *(const bf16x8*)&Kts[nc * 16 + fr][32 + q * 8];
      f32x4 z = {};
      z = __builtin_amdgcn_mfma_f32_16x16x32_bf16(aq0, bk0, z, 0, 0, 0);
      sA[nc] = __builtin_amdgcn_mfma_f32_16x16x32_bf16(aq1, bk1, z, 0, 0, 0);
    }
    float sv[4][4];
    #pragma unroll
    for (int nc = 0; nc < 4; nc++)
      #pragma unroll
      for (int r = 0; r < 4; r++) {
        int row = i0 + band + q * 4 + r;
        int col = j0 + nc * 16 + fr;
        sv[nc][r] = (col <= row) ? sA[nc][r] * C2_C : -1e30f;  // log2 domain
      }
    #pragma unroll
    for (int r = 0; r < 4; r++) {
      float mx = fmaxf(fmaxf(sv[0][r], sv[1][r]), fmaxf(sv[2][r], sv[3][r]));
      #pragma unroll
      for (int off = 1; off < 16; off <<= 1) mx = fmaxf(mx, __shfl_xor(mx, off, 64));
      float mn = fmaxf(m[r], mx);
      float alpha = exp2f(m[r] - mn);
      float ps = 0.f;
      #pragma unroll
      for (int nc = 0; nc < 4; nc++) {
        float p = exp2f(sv[nc][r] - mn);
        Ps[band + q * 4 + r][nc * 16 + fr] = f2bu(p);
        ps += p;
      }
      #pragma unroll
      for (int off = 1; off < 16; off <<= 1) ps += __shfl_xor(ps, off, 64);
      l[r] = l[r] * alpha + ps;
      m[r] = mn;
      #pragma unroll
      for (int nc = 0; nc < 4; nc++) oacc[nc][r] *= alpha;
    }
    bf16x8 ap0 = *(const bf16x8*)&Ps[band + fr][q * 8];
    bf16x8 ap1 = *(const bf16x8*)&Ps[band + fr][32 + q * 8];
    #pragma unroll
    for (int nc = 0; nc < 4; nc++) {
      bf16x8 bv0 = *(const bf16x8*)&Vts[nc * 16 + fr][q * 8];
      bf16x8 bv1 = *(const bf16x8*)&Vts[nc * 16 + fr][32 + q * 8];
      oacc[nc] = __builtin_amdgcn_mfma_f32_16x16x32_bf16(ap0, bv0, oacc[nc], 0, 0, 0);
      oacc[nc] = __builtin_amdgcn_mfma_f32_16x16x32_bf16(ap1, bv1, oacc[nc], 0, 0, 0);
    }
  }
  // epilogue: g = O - Xs (bf16 normal + transposed), Dv partials
  float linv[4];
  #pragma unroll
  for (int r = 0; r < 4; r++) linv[r] = 1.0f / l[r];
  float dpart[4] = {};
  #pragma unroll
  for (int nc = 0; nc < 4; nc++) {
    ushort_t pg[4];
    #pragma unroll
    for (int r = 0; r < 4; r++) {
      int row = i0 + band + q * 4 + r;
      size_t gi = (size_t)(b * S_LEN + row) * E_DIM + h * HD + nc * 16 + fr;
      float o = oacc[nc][r] * linv[r];
      float g = o - Xs[gi];
      ushort_t bu = f2bu(g);
      Gb[gi] = bu;
      pg[r] = bu;
      dpart[r] += g * o;
    }
    int d = nc * 16 + fr;
    int s0 = i0 + band + q * 4;
    *(uint2*)(Gt + ((size_t)bh * HD + d) * S_LEN + s0) = *(uint2*)pg;
  }
  #pragma unroll
  for (int r = 0; r < 4; r++) {
    #pragma unroll
    for (int off = 1; off < 16; off <<= 1) dpart[r] += __shfl_xor(dpart[r], off, 64);
  }
  if (fr == 0) {
    #pragma unroll
    for (int r = 0; r < 4; r++) {
      size_t sid = (size_t)bh * S_LEN + i0 + band + q * 4 + r;
      mbuf[sid] = m[r] + log2f(l[r]);   // m' folds 1/l into the exponent
      Dv[sid] = dpart[r];
    }
  }
}

// ---- merged backward: block (bh, y): dq for i-tile y (y+1 units) then dk/dv for
//      j-tile y (16-y units) = 17 units/block. P = exp2(s*C2 - m'); SC folded into Qt/Kt. ----
__global__ __launch_bounds__(256) void bwd_fused(const ushort_t* __restrict__ Qg,
                                                 const ushort_t* __restrict__ Kg,
                                                 const ushort_t* __restrict__ Vg,
                                                 const ushort_t* __restrict__ Gg,
                                                 const ushort_t* __restrict__ Qt,
                                                 const ushort_t* __restrict__ Kt,
                                                 const ushort_t* __restrict__ Gt,
                                                 const float* __restrict__ mbuf,
                                                 const float* __restrict__ Dv,
                                                 ushort_t* __restrict__ GQ,
                                                 ushort_t* __restrict__ GK,
                                                 ushort_t* __restrict__ GV) {
  int bh = blockIdx.x, y = blockIdx.y;
  int b = bh >> 4, h = bh & 15;
  int tid = threadIdx.x, lane = tid & 63, wv = tid >> 6;
  int fr = lane & 15, q = lane >> 4;
  int band = wv * 16;
  __shared__ ushort_t smem[6][64][72];

  // ================= phase A: dq for i-tile y =================
  {
    ushort_t (*Kts)[72] = smem[0];  // [j][d]
    ushort_t (*Vts)[72] = smem[1];  // [j][d]
    ushort_t (*Ktt)[72] = smem[2];  // [d][j] (pre-scaled by SC)
    ushort_t (*dSs)[72] = smem[3];
    int it = y, i0 = it * 64;

    const ushort_t* Qrow = Qg + (size_t)(b * S_LEN + i0 + band + fr) * E_DIM + h * HD;
    const ushort_t* Grow = Gg + (size_t)(b * S_LEN + i0 + band + fr) * E_DIM + h * HD;
    bf16x8 aq0 = ldg8(Qrow + q * 8), aq1 = ldg8(Qrow + 32 + q * 8);
    bf16x8 ag0 = ldg8(Grow + q * 8), ag1 = ldg8(Grow + 32 + q * 8);

    float mrow[4], Dr[4];
    #pragma unroll
    for (int r = 0; r < 4; r++) {
      size_t sid = (size_t)bh * S_LEN + i0 + band + q * 4 + r;
      mrow[r] = mbuf[sid]; Dr[r] = Dv[sid];
    }
    f32x4 dqacc[4] = {};

    #pragma unroll 1
    for (int jt = 0; jt <= it; jt++) {
      int j0 = jt * 64;
      __syncthreads();
      #pragma unroll
      for (int t = 0; t < 2; t++) {
        int u = tid + 256 * t;
        int r = u >> 3, c8 = (u & 7) * 8;
        *(uint4*)&Kts[r][c8] = *(const uint4*)(Kg + (size_t)(b * S_LEN + j0 + r) * E_DIM + h * HD + c8);
        *(uint4*)&Vts[r][c8] = *(const uint4*)(Vg + (size_t)(b * S_LEN + j0 + r) * E_DIM + h * HD + c8);
        *(uint4*)&Ktt[r][c8] = *(const uint4*)(Kt + (size_t)(bh * HD + r) * S_LEN + j0 + c8);
      }
      __syncthreads();
      f32x4 sA[4], dpA[4];
      #pragma unroll
      for (int nc = 0; nc < 4; nc++) {
        bf16x8 bk0 = *(const bf16x8*)&Kts[nc * 16 + fr][q * 8];
        bf16x8 bk1 = *(const bf16x8*)&Kts[nc * 16 + fr][32 + q * 8];
        bf16x8 bv0 = *(const bf16x8*)&Vts[nc * 16 + fr][q * 8];
        bf16x8 bv1 = *(const bf16x8*)&Vts[nc * 16 + fr][32 + q * 8];
        f32x4 z = {};
        z = __builtin_amdgcn_mfma_f32_16x16x32_bf16(aq0, bk0, z, 0, 0, 0);
        sA[nc] = __builtin_amdgcn_mfma_f32_16x16x32_bf16(aq1, bk1, z, 0, 0, 0);
        f32x4 z2 = {};
        z2 = __builtin_amdgcn_mfma_f32_16x16x32_bf16(ag0, bv0, z2, 0, 0, 0);
        dpA[nc] = __builtin_amdgcn_mfma_f32_16x16x32_bf16(ag1, bv1, z2, 0, 0, 0);
      }
      #pragma unroll
      for (int nc = 0; nc < 4; nc++)
        #pragma unroll
        for (int r = 0; r < 4; r++) {
          int row = i0 + band + q * 4 + r;
          int col = j0 + nc * 16 + fr;
          float ds = 0.f;
          if (col <= row) {
            float P = exp2f(fmaf(sA[nc][r], C2_C, -mrow[r]));
            ds = P * (dpA[nc][r] - Dr[r]);   // SC lives in Kt
          }
          dSs[band + q * 4 + r][nc * 16 + fr] = f2bu(ds);  // wave-private
        }
      bf16x8 ad0 = *(const bf16x8*)&dSs[band + fr][q * 8];
      bf16x8 ad1 = *(const bf16x8*)&dSs[band + fr][32 + q * 8];
      #pragma unroll
      for (int nc = 0; nc < 4; nc++) {
        bf16x8 bt0 = *(const bf16x8*)&Ktt[nc * 16 + fr][q * 8];
        bf16x8 bt1 = *(const bf16x8*)&Ktt[nc * 16 + fr][32 + q * 8];
        dqacc[nc] = __builtin_amdgcn_mfma_f32_16x16x32_bf16(ad0, bt0, dqacc[nc], 0, 0, 0);
        dqacc[nc] = __builtin_amdgcn_mfma_f32_16x16x32_bf16(ad1, bt1, dqacc[nc], 0, 0, 0);
      }
    }
    #pragma unroll
    for (int nc = 0; nc < 4; nc++)
      #pragma unroll
      for (int r = 0; r < 4; r++) {
        int row = i0 + band + q * 4 + r;
        size_t gi = (size_t)(b * S_LEN + row) * E_DIM + h * HD + nc * 16 + fr;
        GQ[gi] = f2bu(dqacc[nc][r]);
      }
  }

  // ================= phase B: dk/dv for j-tile y =================
  {
    ushort_t (*Qs_)[72] = smem[0];  // [i][d]
    ushort_t (*Gs_)[72] = smem[1];  // [i][d]
    ushort_t (*Qtt)[72] = smem[2];  // [d][i] (pre-scaled by SC)
    ushort_t (*Gtt)[72] = smem[3];  // [d][i]
    ushort_t (*PT)[72]  = smem[4];  // [j][i]
    ushort_t (*dST)[72] = smem[5];  // [j][i]
    int jt = y, j0 = jt * 64;

    const ushort_t* Krow = Kg + (size_t)(b * S_LEN + j0 + band + fr) * E_DIM + h * HD;
    const ushort_t* Vrow = Vg + (size_t)(b * S_LEN + j0 + band + fr) * E_DIM + h * HD;
    bf16x8 ak0 = ldg8(Krow + q * 8), ak1 = ldg8(Krow + 32 + q * 8);
    bf16x8 av0 = ldg8(Vrow + q * 8), av1 = ldg8(Vrow + 32 + q * 8);

    f32x4 dkacc[4] = {}, dvacc[4] = {};

    #pragma unroll 1
    for (int i_t = jt; i_t < 16; i_t++) {
      int i0 = i_t * 64;
      __syncthreads();
      #pragma unroll
      for (int t = 0; t < 2; t++) {
        int u = tid + 256 * t;
        int r = u >> 3, c8 = (u & 7) * 8;
        *(uint4*)&Qs_[r][c8] = *(const uint4*)(Qg + (size_t)(b * S_LEN + i0 + r) * E_DIM + h * HD + c8);
        *(uint4*)&Gs_[r][c8] = *(const uint4*)(Gg + (size_t)(b * S_LEN + i0 + r) * E_DIM + h * HD + c8);
        *(uint4*)&Qtt[r][c8] = *(const uint4*)(Qt + (size_t)(bh * HD + r) * S_LEN + i0 + c8);
        *(uint4*)&Gtt[r][c8] = *(const uint4*)(Gt + (size_t)(bh * HD + r) * S_LEN + i0 + c8);
      }
      __syncthreads();
      float mc[4], Dc[4];
      #pragma unroll
      for (int nc = 0; nc < 4; nc++) {
        size_t sid = (size_t)bh * S_LEN + i0 + nc * 16 + fr;
        mc[nc] = mbuf[sid]; Dc[nc] = Dv[sid];
      }
      f32x4 stA[4], dptA[4];
      #pragma unroll
      for (int nc = 0; nc < 4; nc++) {
        bf16x8 bq0 = *(const bf16x8*)&Qs_[nc * 16 + fr][q * 8];
        bf16x8 bq1 = *(const bf16x8*)&Qs_[nc * 16 + fr][32 + q * 8];
        bf16x8 bg0 = *(const bf16x8*)&Gs_[nc * 16 + fr][q * 8];
        bf16x8 bg1 = *(const bf16x8*)&Gs_[nc * 16 + fr][32 + q * 8];
        f32x4 z = {};
        z = __builtin_amdgcn_mfma_f32_16x16x32_bf16(ak0, bq0, z, 0, 0, 0);
        stA[nc] = __builtin_amdgcn_mfma_f32_16x16x32_bf16(ak1, bq1, z, 0, 0, 0);
        f32x4 z2 = {};
        z2 = __builtin_amdgcn_mfma_f32_16x16x32_bf16(av0, bg0, z2, 0, 0, 0);
        dptA[nc] = __builtin_amdgcn_mfma_f32_16x16x32_bf16(av1, bg1, z2, 0, 0, 0);
      }
      #pragma unroll
      for (int nc = 0; nc < 4; nc++)
        #pragma unroll
        for (int r = 0; r < 4; r++) {
          int jrow = j0 + band + q * 4 + r;
          int icol = i0 + nc * 16 + fr;
          float P = 0.f, ds = 0.f;
          if (icol >= jrow) {
            P = exp2f(fmaf(stA[nc][r], C2_C, -mc[nc]));
            ds = P * (dptA[nc][r] - Dc[nc]);   // SC lives in Qt
          }
          PT[band + q * 4 + r][nc * 16 + fr] = f2bu(P);   // wave-private
          dST[band + q * 4 + r][nc * 16 + fr] = f2bu(ds);
        }
      bf16x8 ap0 = *(const bf16x8*)&PT[band + fr][q * 8];
      bf16x8 ap1 = *(const bf16x8*)&PT[band + fr][32 + q * 8];
      bf16x8 ad0 = *(const bf16x8*)&dST[band + fr][q * 8];
      bf16x8 ad1 = *(const bf16x8*)&dST[band + fr][32 + q * 8];
      #pragma unroll
      for (int nc = 0; nc < 4; nc++) {
        bf16x8 bg0 = *(const bf16x8*)&Gtt[nc * 16 + fr][q * 8];
        bf16x8 bg1 = *(const bf16x8*)&Gtt[nc * 16 + fr][32 + q * 8];
        bf16x8 bq0 = *(const bf16x8*)&Qtt[nc * 16 + fr][q * 8];
        bf16x8 bq1 = *(const bf16x8*)&Qtt[nc * 16 + fr][32 + q * 8];
        dvacc[nc] = __builtin_amdgcn_mfma_f32_16x16x32_bf16(ap0, bg0, dvacc[nc], 0, 0, 0);
        dvacc[nc] = __builtin_amdgcn_mfma_f32_16x16x32_bf16(ap1, bg1, dvacc[nc], 0, 0, 0);
        dkacc[nc] = __builtin_amdgcn_mfma_f32_16x16x32_bf16(ad0, bq0, dkacc[nc], 0, 0, 0);
        dkacc[nc] = __builtin_amdgcn_mfma_f32_16x16x32_bf16(ad1, bq1, dkacc[nc], 0, 0, 0);
      }
    }
    #pragma unroll
    for (int nc = 0; nc < 4; nc++)
      #pragma unroll
      for (int r = 0; r < 4; r++) {
        int jrow = j0 + band + q * 4 + r;
        size_t gi = (size_t)(b * S_LEN + jrow) * E_DIM + h * HD + nc * 16 + fr;
        GK[gi] = f2bu(dkacc[nc][r]);
        GV[gi] = f2bu(dvacc[nc][r]);
      }
  }
}

// ---------------- launch ----------------
extern "C" void kernel_launch(void* const* d_in, const int* in_sizes, int n_in,
                              void* d_out, int out_size, void* d_ws, size_t ws_size,
                              hipStream_t stream) {
  const float* T1 = (const float*)d_in[0];
  const float* Wq = (const float*)d_in[1];
  const float* Wk = (const float*)d_in[2];
  const float* Wv = (const float*)d_in[3];
  const float* Wo = (const float*)d_in[4];

  const size_t M2 = 2097152;   // 2048*1024
  const size_t M1 = 1048576;
  float* w = (float*)d_ws;
  float* Xs = w;                       // 8 MB fp32 target
  float* mS = Xs + M2;                 // 64K f32 (stores m')
  float* DvS = mS + 65536;
  ushort_t* u = (ushort_t*)(DvS + 65536);
  ushort_t* W0 = u;          ushort_t* W1 = W0 + M1;  ushort_t* W2 = W1 + M1;
  ushort_t* W3 = W2 + M1;    ushort_t* W4 = W3 + M1;  ushort_t* W5 = W4 + M1;
  ushort_t* Qb = W5 + M1;    ushort_t* Kb = Qb + M2;  ushort_t* Vb = Kb + M2;
  ushort_t* Qt = Vb + M2;    ushort_t* Kt = Qt + M2;  ushort_t* Vt = Kt + M2;
  ushort_t* Gt = Vt + M2;
  ushort_t* Gb = Gt + M2;
  ushort_t* GQb = Gb + M2;   ushort_t* GKb = GQb + M2; ushort_t* GVb = GKb + M2;
  ushort_t* X2b = GVb + M2;
  float* X2 = (float*)d_out;

  // stage-1 aliases (all overwritten before stage-2 uses the slots)
  float* Mf  = (float*)Qb;       // 4 MB
  float* M2f = (float*)Kb;       // 4 MB
  ushort_t* Mb  = Gt;            // 2 MB
  ushort_t* Nb  = Vb;            // 2 MB
  ushort_t* AtB = Qt;            // 2 MB
  ushort_t* T1b = Kt;            // 4 MB

  hipMemsetAsync(X2, 0, M2 * sizeof(float), stream);
  hipMemsetAsync(X2b, 0, M2 * sizeof(ushort_t), stream);

  dim3 pgrid(16, 16);
  dim3 sgrid(16, 16);       // 1024x1024 GEMMs
  dim3 ggrid(16, 32);       // 2048x1024 GEMMs
  dim3 ggrid3(16, 32, 3);   // QKV
  dim3 agrid(BH_CNT, 16);   // attention

  // ---- stage 1 (algebraic): Xs = T * Wo * (3LR·I - 3LR²·M + LR³·M²),  M = WoᵀWo ----
  k_cast<<<(M2 / 4 + 255) / 256, 256, 0, stream>>>(T1, T1b, (int)(M2 / 4));
  prep_w<<<pgrid, 256, 0, stream>>>(Wo, W0, W1);
  // M = W1·W1ᵀ  (fp32 + bf16)
  gemm_mf<4, 1><<<sgrid, 256, 0, stream>>>(W1, nullptr, nullptr, W1, nullptr, nullptr,
                                           Mf, Mb, nullptr, nullptr,
                                           nullptr, nullptr, nullptr, 0.f);
  // M2 = Mb·Mbᵀ (M symmetric)
  gemm_mf<3, 1><<<sgrid, 256, 0, stream>>>(Mb, nullptr, nullptr, Mb, nullptr, nullptr,
                                           M2f, nullptr, nullptr, nullptr,
                                           nullptr, nullptr, nullptr, 0.f);
  k_formN<<<(M1 + 255) / 256, 256, 0, stream>>>(Mf, M2f, Nb);
  // AtB = N·Woᵀ  (symmetric N; this is (Wo·N)ᵀ in [N,K] form)
  gemm_mf<5, 1><<<sgrid, 256, 0, stream>>>(Nb, nullptr, nullptr, W0, nullptr, nullptr,
                                           nullptr, AtB, nullptr, nullptr,
                                           nullptr, nullptr, nullptr, 0.f);
  // stage-2 weights (W0/W1 free after AtB)
  prep_w<<<pgrid, 256, 0, stream>>>(Wq, W0, W3);
  prep_w<<<pgrid, 256, 0, stream>>>(Wk, W1, W4);
  prep_w<<<pgrid, 256, 0, stream>>>(Wv, W2, W5);
  // Xs = T1b·AtBᵀ (fp32)
  gemm_mf<3, 1><<<ggrid, 256, 0, stream>>>(T1b, nullptr, nullptr, AtB, nullptr, nullptr,
                                           Xs, nullptr, nullptr, nullptr,
                                           nullptr, nullptr, nullptr, 0.f);

  // ---- stage 2 ----
  for (int t = 0; t < 3; t++) {
    gemm_mf<0, 1><<<ggrid3, 256, 0, stream>>>(X2b, nullptr, nullptr, W0, W1, W2,
                                              nullptr, Qb, Kb, Vb,
                                              Qt, Kt, Vt, 0.f);
    fwd_fused<<<agrid, 256, 0, stream>>>(Qb, Kb, Vt, Xs, mS, Gb, Gt, DvS);
    bwd_fused<<<agrid, 256, 0, stream>>>(Qb, Kb, Vb, Gb, Qt, Kt, Gt, mS, DvS,
                                         GQb, GKb, GVb);
    gemm_mf<2, 3><<<ggrid, 256, 0, stream>>>(GQb, GKb, GVb, W3, W4, W5,
                                             X2, X2b, nullptr, nullptr,
                                             nullptr, nullptr, nullptr, -LR_C);
  }
}